// Round 6
// baseline (105.815 us; speedup 1.0000x reference)
//
#include <hip/hip_runtime.h>

// RecurrentDiscriminator round 6: structural 2-step-ahead obs prefetch.
// - Double-buffered raw obs (A=even steps, B=odd): loads for s+2 issued in
//   step s, consumed at top of s+2 -> cover >= one full step regardless of
//   scheduler placement. sched_barrier(0) pins issue to step top.
// - W1 resident f16x2 in ~150 arch VGPRs; W2/W3 (100) + accInit (10) in AGPRs.
// - Accumulators/state/tanh f32; weights+activations f16 via v_dot2_f32_f16.

#define NB   65536
#define NS   64
#define OBSD 20
#define NH   10

typedef __fp16 f16x2 __attribute__((ext_vector_type(2)));

#define KEEP(x) asm volatile("" : "+v"(x))

__device__ __forceinline__ float ftanh(float x) {
    float e = __builtin_amdgcn_exp2f(x * 2.885390081777927f);  // 2*log2(e)
    float r = __builtin_amdgcn_rcpf(1.0f + e);
    return fmaf(-2.0f, r, 1.0f);
}

__device__ __forceinline__ f16x2 pk(float a, float b) {
    return __builtin_amdgcn_cvt_pkrtz(a, b);
}

#if __has_builtin(__builtin_amdgcn_fdot2)
__device__ __forceinline__ float dot2(f16x2 a, f16x2 b, float c) {
    return __builtin_amdgcn_fdot2(a, b, c, false);
}
#else
__device__ __forceinline__ float dot2(f16x2 a, f16x2 b, float c) {
    return fmaf((float)a[0], (float)b[0], fmaf((float)a[1], (float)b[1], c));
}
#endif

__device__ __forceinline__ void agpr_put(float& slot, float v) {
    asm volatile("v_accvgpr_write_b32 %0, %1" : "=a"(slot) : "v"(v));
}
__device__ __forceinline__ float agpr_getf(const float& slot) {
    float f;
    asm volatile("v_accvgpr_read_b32 %0, %1" : "=v"(f) : "a"(slot));
    return f;
}
__device__ __forceinline__ f16x2 agpr_geth(const float& slot) {
    float f;
    asm volatile("v_accvgpr_read_b32 %0, %1" : "=v"(f) : "a"(slot));
    return __builtin_bit_cast(f16x2, f);
}

__global__ __launch_bounds__(256, 1)
void rd_fwd(const float* __restrict__ states, const float* __restrict__ actions,
            const float* __restrict__ W1, const float* __restrict__ b1,
            const float* __restrict__ W2, const float* __restrict__ b2,
            const float* __restrict__ W3, const float* __restrict__ b3,
            const float* __restrict__ Wg1, const float* __restrict__ bg1,
            const float* __restrict__ Wg2, const float* __restrict__ bg2,
            float* __restrict__ out)
{
    const int b = blockIdx.x * blockDim.x + threadIdx.x;
    const float* __restrict__ row = states + (size_t)b * (NS * OBSD);

    // ---- W1 pair-rows 0..14 resident f16x2, pinned to VGPRs ----
    f16x2 w1p[15 * NH];
#pragma unroll
    for (int p = 0; p < 15; ++p)
#pragma unroll
        for (int o = 0; o < NH; ++o)
            w1p[p * NH + o] = pk(W1[(2 * p) * NH + o], W1[(2 * p + 1) * NH + o]);
#pragma unroll
    for (int i = 0; i < 15 * NH; ++i) KEEP(w1p[i]);

    // ---- accInit = b1 + a0*W1row30 + a1*W1row31 (per-lane f32) -> AGPR ----
    const float a0 = actions[2 * b];
    const float a1 = actions[2 * b + 1];
    float accInit_a[NH];
#pragma unroll
    for (int o = 0; o < NH; ++o) {
        float v = fmaf(a0, W1[30 * NH + o], fmaf(a1, W1[31 * NH + o], b1[o]));
        agpr_put(accInit_a[o], v);
    }

    // ---- W2/W3 packed f16x2 -> AGPRs ----
    float aw2[5 * NH], aw3[5 * NH];
#pragma unroll
    for (int p = 0; p < 5; ++p)
#pragma unroll
        for (int o = 0; o < NH; ++o) {
            agpr_put(aw2[p * NH + o],
                     __builtin_bit_cast(float, pk(W2[(2 * p) * NH + o], W2[(2 * p + 1) * NH + o])));
            agpr_put(aw3[p * NH + o],
                     __builtin_bit_cast(float, pk(W3[(2 * p) * NH + o], W3[(2 * p + 1) * NH + o])));
        }

    float b2r[NH], b3r[NH];
#pragma unroll
    for (int o = 0; o < NH; ++o) { b2r[o] = b2[o]; b3r[o] = b3[o]; }

    float st[NH];
#pragma unroll
    for (int o = 0; o < NH; ++o) st[o] = 0.0f;

    // ---- double-buffered raw obs prefetch: A=even steps, B=odd ----
    float4 A0 = *(const float4*)(row + 0);
    float4 A1 = *(const float4*)(row + 4);
    float4 A2 = *(const float4*)(row + 8);
    float4 A3 = *(const float4*)(row + 12);
    float4 A4 = *(const float4*)(row + 16);
    float4 B0 = *(const float4*)(row + OBSD + 0);
    float4 B1 = *(const float4*)(row + OBSD + 4);
    float4 B2 = *(const float4*)(row + OBSD + 8);
    float4 B3 = *(const float4*)(row + OBSD + 12);
    float4 B4 = *(const float4*)(row + OBSD + 16);

    auto step_body = [&](float4& m0, float4& m1, float4& m2, float4& m3,
                         float4& m4, int sn) {
        // consume prefetched obs (counted vmcnt wait), pack to f16x2
        f16x2 obsP[10];
        obsP[0] = pk(m0.x, m0.y); obsP[1] = pk(m0.z, m0.w);
        obsP[2] = pk(m1.x, m1.y); obsP[3] = pk(m1.z, m1.w);
        obsP[4] = pk(m2.x, m2.y); obsP[5] = pk(m2.z, m2.w);
        obsP[6] = pk(m3.x, m3.y); obsP[7] = pk(m3.z, m3.w);
        obsP[8] = pk(m4.x, m4.y); obsP[9] = pk(m4.z, m4.w);

        // reuse regs: issue loads for step sn (2 ahead), pinned to step top
        {
            const float* pf = row + sn * OBSD;
            m0 = *(const float4*)(pf + 0);
            m1 = *(const float4*)(pf + 4);
            m2 = *(const float4*)(pf + 8);
            m3 = *(const float4*)(pf + 12);
            m4 = *(const float4*)(pf + 16);
        }
        __builtin_amdgcn_sched_barrier(0);

        f16x2 stp[5];
#pragma unroll
        for (int p = 0; p < 5; ++p) stp[p] = pk(st[2 * p], st[2 * p + 1]);

        // ---- layer 1 ----
        float acc[NH];
#pragma unroll
        for (int o = 0; o < NH; ++o) acc[o] = agpr_getf(accInit_a[o]);
#pragma unroll
        for (int p = 0; p < 5; ++p)
#pragma unroll
            for (int o = 0; o < NH; ++o) acc[o] = dot2(stp[p], w1p[p * NH + o], acc[o]);
#pragma unroll
        for (int p = 0; p < 10; ++p)
#pragma unroll
            for (int o = 0; o < NH; ++o) acc[o] = dot2(obsP[p], w1p[(5 + p) * NH + o], acc[o]);
#pragma unroll
        for (int o = 0; o < NH; ++o) acc[o] = ftanh(acc[o]);

        f16x2 h1p[5];
#pragma unroll
        for (int p = 0; p < 5; ++p) h1p[p] = pk(acc[2 * p], acc[2 * p + 1]);

        // ---- layer 2 (W2 from AGPR) ----
        float acc2[NH];
#pragma unroll
        for (int o = 0; o < NH; ++o) acc2[o] = b2r[o];
#pragma unroll
        for (int p = 0; p < 5; ++p)
#pragma unroll
            for (int o = 0; o < NH; ++o)
                acc2[o] = dot2(h1p[p], agpr_geth(aw2[p * NH + o]), acc2[o]);
#pragma unroll
        for (int o = 0; o < NH; ++o) acc2[o] = ftanh(acc2[o]);

        f16x2 h2p[5];
#pragma unroll
        for (int p = 0; p < 5; ++p) h2p[p] = pk(acc2[2 * p], acc2[2 * p + 1]);

        // ---- layer 3 (W3 from AGPR) ----
#pragma unroll
        for (int o = 0; o < NH; ++o) st[o] += b3r[o];
#pragma unroll
        for (int p = 0; p < 5; ++p)
#pragma unroll
            for (int o = 0; o < NH; ++o)
                st[o] = dot2(h2p[p], agpr_geth(aw3[p * NH + o]), st[o]);
    };

#pragma unroll 1
    for (int s = 0; s < NS; s += 2) {
        int sa = s + 2; if (sa > NS - 1) sa = NS - 1;
        int sb = s + 3; if (sb > NS - 1) sb = NS - 1;
        step_body(A0, A1, A2, A3, A4, sa);
        step_body(B0, B1, B2, B3, B4, sb);
    }

    // ---- head (once, f32, uniform weights) ----
    float g[NH];
#pragma unroll
    for (int o = 0; o < NH; ++o) {
        float a = bg1[o];
#pragma unroll
        for (int i = 0; i < NH; ++i) a = fmaf(st[i], Wg1[i * NH + o], a);
        g[o] = ftanh(a);
    }
    float r = bg2[0];
#pragma unroll
    for (int o = 0; o < NH; ++o) r = fmaf(g[o], Wg2[o], r);
    out[b] = r;
}

extern "C" void kernel_launch(void* const* d_in, const int* in_sizes, int n_in,
                              void* d_out, int out_size, void* d_ws, size_t ws_size,
                              hipStream_t stream) {
    const float* states  = (const float*)d_in[0];
    const float* actions = (const float*)d_in[1];
    const float* W1  = (const float*)d_in[2];
    const float* b1  = (const float*)d_in[3];
    const float* W2  = (const float*)d_in[4];
    const float* b2  = (const float*)d_in[5];
    const float* W3  = (const float*)d_in[6];
    const float* b3  = (const float*)d_in[7];
    const float* Wg1 = (const float*)d_in[8];
    const float* bg1 = (const float*)d_in[9];
    const float* Wg2 = (const float*)d_in[10];
    const float* bg2 = (const float*)d_in[11];
    float* out = (float*)d_out;

    rd_fwd<<<NB / 256, 256, 0, stream>>>(states, actions, W1, b1, W2, b2,
                                         W3, b3, Wg1, bg1, Wg2, bg2, out);
}